// Round 14
// baseline (199.533 us; speedup 1.0000x reference)
//
#include <hip/hip_runtime.h>
#include <cstdint>

// DetNet NMS, round 14: FULL FUSION into one kernel.
// r13 null result: launch_bounds changed nothing (VGPR stayed 40) — the
// compiler sinks prefetch state regardless of budget; k3-at-source is a
// local fixed point (~46us). Remaining budget: ~58us of k2+k_mask+launch
// gaps. This round deletes the gaps: one kernel, 128 blocks x 512 threads
// (1/CU, trivially co-resident), hand-rolled agent-scope grid barrier
// (counter+generation in ws, memset to 0 via hipMemsetAsync each launch).
//   Phase 1 (all blocks): build keys in LDS (identical per block; V stays in
//     LDS — no global vcnt), ballot-compact, V^2 rank scan, scatter sorted
//     boxes + d rows, zero out slice, zero dummy row.   [= r9-13 k2]
//   barrier (agent fence: boxes/d_srt visible cross-XCD)
//   Phase 2 (all blocks): suppression-bit matrix; block loops over 8 of the
//     1024 (64-row x 16-word) tiles, triangle/V-pruned.  [= k_mask]
//   barrier (mask visible)
//   Phase 3 (block 0): r12's verified producer/consumer greedy resolve
//     (resolver wave: SALU+readlane; 7 helper waves: kept-row ORs into LDS
//     dead-vector); other blocks exit after barrier 2.
// All decision-critical FP math __f*_rn in exact ref op order (absmax 0.0,
// rounds 1-4, 6-9, 11-13).

#define M_TOT 8192
#define NMS_T 0.3f
#define NBLK  128

// ws layout (bytes)
#define WS_BOX   65536      // float4[8192]
#define WS_D     196608     // float[40960]
#define WS_BAR   360448     // u32 cnt, u32 gen (memset 0 each launch)
#define WS_ZROW  393216     // u64[128] dummy zero row
#define WS_MASK  524288     // u64[8192*128] = 8 MB

typedef unsigned long long u64t;

__device__ __forceinline__ uint32_t desc_key(float sv) {
    uint32_t u = __float_as_uint(sv);
    uint32_t m = (u & 0x80000000u) ? ~u : (u | 0x80000000u);
    return ~m;
}
__device__ __forceinline__ u64t rdl64(u64t v, int sl) {
    unsigned lo = (unsigned)__builtin_amdgcn_readlane((int)(unsigned)v, sl);
    unsigned hi = (unsigned)__builtin_amdgcn_readlane((int)(unsigned)(v >> 32), sl);
    return ((u64t)hi << 32) | lo;
}
__device__ __forceinline__ u64t rdfl64(u64t v) {
    unsigned lo = (unsigned)__builtin_amdgcn_readfirstlane((int)(unsigned)v);
    unsigned hi = (unsigned)__builtin_amdgcn_readfirstlane((int)(unsigned)(v >> 32));
    return ((u64t)hi << 32) | lo;
}

// device-scope two-phase grid barrier; cnt/gen zeroed by hipMemsetAsync
__device__ __forceinline__ void gbar(unsigned* cnt, unsigned* gen, int tid) {
    __syncthreads();
    if (tid == 0) {
        unsigned g = __hip_atomic_load(gen, __ATOMIC_RELAXED, __HIP_MEMORY_SCOPE_AGENT);
        __threadfence();                                   // release our writes
        unsigned a = __hip_atomic_fetch_add(cnt, 1u, __ATOMIC_ACQ_REL,
                                            __HIP_MEMORY_SCOPE_AGENT);
        if (a + 1u == (unsigned)NBLK) {
            __hip_atomic_store(cnt, 0u, __ATOMIC_RELAXED, __HIP_MEMORY_SCOPE_AGENT);
            __hip_atomic_fetch_add(gen, 1u, __ATOMIC_RELEASE, __HIP_MEMORY_SCOPE_AGENT);
        } else {
            while (__hip_atomic_load(gen, __ATOMIC_ACQUIRE,
                                     __HIP_MEMORY_SCOPE_AGENT) == g)
                __builtin_amdgcn_s_sleep(2);
        }
        __threadfence();                                   // acquire remote writes
    }
    __syncthreads();
}

__device__ __forceinline__ void scatter_one(
    int i, int rank, u64t key,
    const float* __restrict__ det, const float* __restrict__ offsets,
    const float* __restrict__ scales,
    float4* __restrict__ boxes_srt, float* __restrict__ d_srt)
{
    uint32_t dkey = (uint32_t)(key >> 16);
    if (dkey >= 0x7FFFFFFFu) return;     // score <= 0: row stays zero
    int g = i >> 10;
    float d0 = __fadd_rn(offsets[g*5+0], __fmul_rn(det[i*5+0], scales[g*5+0]));
    float d1 = __fadd_rn(offsets[g*5+1], __fmul_rn(det[i*5+1], scales[g*5+1]));
    float d2 = __fadd_rn(offsets[g*5+2], __fmul_rn(det[i*5+2], scales[g*5+2]));
    float d3 = __fadd_rn(offsets[g*5+3], __fmul_rn(det[i*5+3], scales[g*5+3]));
    float d4 = __fadd_rn(offsets[g*5+4], __fmul_rn(det[i*5+4], scales[g*5+4]));
    d_srt[rank*5+0] = d0; d_srt[rank*5+1] = d1; d_srt[rank*5+2] = d2;
    d_srt[rank*5+3] = d3; d_srt[rank*5+4] = d4;
    float hw = __fmul_rn(d3, 0.5f), hh = __fmul_rn(d4, 0.5f);
    boxes_srt[rank] = make_float4(__fsub_rn(d1, hw), __fsub_rn(d2, hh),
                                  __fadd_rn(d1, hw), __fadd_rn(d2, hh));
}

struct WSlot { ulonglong2 dl, dh, n1l, n1h, n2l, n2h; };

__device__ __forceinline__ void fill_words(
    const u64t* __restrict__ mask, int lane, int T, WSlot& w)
{
    int rl = min(T * 128 + lane,      M_TOT - 1);
    int rh = min(T * 128 + 64 + lane, M_TOT - 1);
    const ulonglong2* mrl = (const ulonglong2*)(mask + (size_t)rl * 128);
    const ulonglong2* mrh = (const ulonglong2*)(mask + (size_t)rh * 128);
    int p0 = min(T, 63), p1 = min(T + 1, 63), p2 = min(T + 2, 63);
    w.dl  = mrl[p0]; w.dh  = mrh[p0];
    w.n1l = mrl[p1]; w.n1h = mrh[p1];
    w.n2l = mrl[p2]; w.n2h = mrh[p2];
}

__device__ __forceinline__ void res_step(
    const u64t* __restrict__ mask,
    u64t* sdead, u64t* ck, volatile int* res_prog, volatile int* h_prog,
    int lane, int T,
    u64t& cA_lo, u64t& cA_hi, u64t& cB_lo, u64t& cB_hi, WSlot& w)
{
    if (T >= 3) {
        int need = T - 2;
        while (true) {
            int hp = (lane < 7) ? h_prog[lane] : 0x7FFFFFFF;
            if (__ballot(hp < need) == 0ull) break;
        }
    }
    u64t dlo = rdfl64(((volatile u64t*)sdead)[2 * T]);
    u64t dhi = rdfl64(((volatile u64t*)sdead)[2 * T + 1]);
    u64t live_lo = ~(dlo | cA_lo);
    u64t live_hi = ~(dhi | cA_hi);
    u64t km_lo = 0, km_hi = 0;
    while (live_lo) {
        int bs = (int)__builtin_ctzll(live_lo);
        km_lo |= 1ull << bs;
        u64t rml = rdl64(w.dl.x, bs);
        u64t rmh = rdl64(w.dl.y, bs);
        live_lo &= ~rml & ~(1ull << bs);
        live_hi &= ~rmh;
    }
    while (live_hi) {
        int bs = (int)__builtin_ctzll(live_hi);
        km_hi |= 1ull << bs;
        u64t rmh = rdl64(w.dh.y, bs);   // w.dh.x may be garbage: low word done
        live_hi &= ~rmh & ~(1ull << bs);
    }
    if (lane == 0) { ck[2 * T] = km_lo; ck[2 * T + 1] = km_hi; }
    __threadfence_block();
    if (lane == 0) *res_prog = T + 1;
    u64t c1l = 0, c1h = 0, c2l = 0, c2h = 0, km = km_lo;
    while (km) {
        int b = (int)__builtin_ctzll(km); km &= km - 1;
        c1l |= rdl64(w.n1l.x, b); c1h |= rdl64(w.n1l.y, b);
        c2l |= rdl64(w.n2l.x, b); c2h |= rdl64(w.n2l.y, b);
    }
    km = km_hi;
    while (km) {
        int b = (int)__builtin_ctzll(km); km &= km - 1;
        c1l |= rdl64(w.n1h.x, b); c1h |= rdl64(w.n1h.y, b);
        c2l |= rdl64(w.n2h.x, b); c2h |= rdl64(w.n2h.y, b);
    }
    cA_lo = cB_lo | c1l; cA_hi = cB_hi | c1h;
    cB_lo = c2l;         cB_hi = c2h;
    fill_words(mask, lane, T + 3, w);
}

__global__ __launch_bounds__(512) void k_all(
    const float* __restrict__ det, const float* __restrict__ offsets,
    const float* __restrict__ scales, const float* __restrict__ bounds,
    float4* __restrict__ boxes_srt, float* __restrict__ d_srt,
    u64t* __restrict__ zrow, u64t* __restrict__ mask,
    unsigned* __restrict__ bar, float* __restrict__ out)
{
    __shared__ u64t skey[M_TOT];                 // 64 KB
    __shared__ float soff[40], sscl[40], sbnd[32];
    __shared__ int sTop;
    __shared__ float4 sb[16 * 65];
    __shared__ float  sa[16 * 65];
    __shared__ u64t sdead[128];
    __shared__ u64t ck[128];
    __shared__ int  res_prog;
    __shared__ int  h_prog[7];

    int t = threadIdx.x, lane = t & 63, wv = t >> 6;
    unsigned* cnt = bar;
    unsigned* gen = bar + 1;

    // ================= Phase 1: keys, compact, rank, scatter ==============
    if (t == 0) sTop = 0;
    if (t < 40) { soff[t] = offsets[t]; sscl[t] = scales[t]; }
    if (t < 32) { sbnd[t] = bounds[t]; }
    if (blockIdx.x == 0 && t < 128) zrow[t] = 0ull;
    __syncthreads();

    #pragma unroll 4
    for (int s = 0; s < 16; ++s) {
        int u = s * 512 + t;
        int g = u >> 10;
        float raw_s = det[u * 5 + 0];
        float cx    = det[u * 5 + 1];
        float cy    = det[u * 5 + 2];
        float score = __fadd_rn(soff[g * 5 + 0], __fmul_rn(raw_s, sscl[g * 5 + 0]));
        bool valid = (cx < sbnd[g*4+1]) && (cx > sbnd[g*4+0]) &&
                     (cy < sbnd[g*4+3]) && (cy > sbnd[g*4+2]);
        float sv = valid ? score : -1.0f;
        uint32_t dk = desc_key(sv);
        bool push = dk < 0x7FFFFFFFu;
        u64t key = ((u64t)dk << 16) | (unsigned)u;
        u64t bal = __ballot(push);
        if (bal) {
            int lw = 0;
            if (lane == 0) lw = atomicAdd(&sTop, __popcll(bal));
            int wbase = __builtin_amdgcn_readfirstlane(lw);
            if (push) {
                int off = __popcll(bal & ((1ull << lane) - 1ull));
                skey[wbase + off] = key;
            }
        }
    }
    __syncthreads();
    int V = sTop;
    int Vpad = (V + 15) & ~15;
    if (t < Vpad - V) skey[V + t] = ~0ull;
    {   // zero this block's slice of out (harness poisons to 0xAA)
        int zb = blockIdx.x * 320;
        for (int z = zb + t; z < zb + 320; z += 512) out[z] = 0.0f;
    }
    __syncthreads();

    {   // rank scan: 64 groups of 8 lanes; group -> one original index i
        int grp = t >> 3, jq = t & 7;
        int i = blockIdx.x * 64 + grp;           // 128*64 = 8192
        int g = i >> 10;
        float raw_s = det[i * 5 + 0];
        float cx    = det[i * 5 + 1];
        float cy    = det[i * 5 + 2];
        float score = __fadd_rn(soff[g * 5 + 0], __fmul_rn(raw_s, sscl[g * 5 + 0]));
        bool valid = (cx < sbnd[g*4+1]) && (cx > sbnd[g*4+0]) &&
                     (cy < sbnd[g*4+3]) && (cy > sbnd[g*4+2]);
        float sv = valid ? score : -1.0f;
        uint32_t dk = desc_key(sv);
        u64t ki = ((u64t)dk << 16) | (unsigned)i;
        const ulonglong2* skey2 = (const ulonglong2*)skey;
        int c = 0;
        int nit = Vpad >> 4;
        #pragma unroll 4
        for (int it = 0; it < nit; ++it) {
            ulonglong2 kj = skey2[it * 8 + jq];
            c += (kj.x < ki) + (kj.y < ki);
        }
        c += __shfl_xor(c, 1);
        c += __shfl_xor(c, 2);
        c += __shfl_xor(c, 4);
        if (jq == 0)
            scatter_one(i, c, ki, det, offsets, scales, boxes_srt, d_srt);
    }

    gbar(cnt, gen, t);   // boxes_srt/d_srt visible device-wide

    // ================= Phase 2: suppression-bit matrix ====================
    {
        int ncw = (V + 63) >> 6;
        for (int tile = blockIdx.x; tile < 128 * 8; tile += NBLK) {
            int bx = tile >> 3, by = tile & 7;   // rows [64bx,+64), words [16by,+16)
            if (bx * 64 >= V) continue;
            if (by * 1024 >= V) continue;
            if (by * 16 + 15 < (bx * 64) >> 6) continue;
            __syncthreads();                     // prior tile's readers done
            int cbase = by * 1024;
            for (int u = t; u < 1024; u += 512) {
                float4 b = boxes_srt[cbase + u];
                int c = u >> 6, jj = u & 63;
                sb[c * 65 + jj] = b;
                sa[c * 65 + jj] = __fmul_rn(fmaxf(__fsub_rn(b.z, b.x), 0.0f),
                                            fmaxf(__fsub_rn(b.w, b.y), 0.0f));
            }
            __syncthreads();
            int r = bx * 64 + (t >> 3);
            if (r >= V) continue;
            float4 bi = boxes_srt[r];
            float ai = __fmul_rn(fmaxf(__fsub_rn(bi.z, bi.x), 0.0f),
                                 fmaxf(__fsub_rn(bi.w, bi.y), 0.0f));
            int rw = r >> 6;
            #pragma unroll
            for (int k = 0; k < 2; ++k) {
                int wl = (t & 7) + k * 8;
                int w = by * 16 + wl;
                if (w < rw || w >= ncw) continue;
                u64t bits = 0;
                #pragma unroll 4
                for (int jj = 0; jj < 64; ++jj) {
                    float4 bj = sb[wl * 65 + jj];
                    float aj = sa[wl * 65 + jj];
                    float iw = fmaxf(__fsub_rn(fminf(bi.z, bj.z), fmaxf(bi.x, bj.x)), 0.0f);
                    float ih = fmaxf(__fsub_rn(fminf(bi.w, bj.w), fmaxf(bi.y, bj.y)), 0.0f);
                    float inter = __fmul_rn(iw, ih);
                    float uni   = __fsub_rn(__fadd_rn(ai, aj), inter);
                    float iou   = __fdiv_rn(inter, fmaxf(uni, 1e-9f));
                    int j = w * 64 + jj;
                    if (j > r && iou > NMS_T) bits |= 1ull << jj;
                }
                mask[(size_t)r * 128 + w] = bits;
            }
        }
    }

    gbar(cnt, gen, t);   // mask visible device-wide

    // ================= Phase 3: greedy resolve (block 0 only) =============
    if (blockIdx.x != 0) return;
    int nc = (V + 127) >> 7;
    if (t < 128) {
        int bw = t * 64;
        u64t w0 = 0;
        if (bw >= V)           w0 = ~0ull;
        else if (bw + 64 > V)  w0 = (~0ull) << (V - bw);
        sdead[t] = w0;
        ck[t] = 0ull;
    }
    if (t == 0) res_prog = 0;
    if (t < 7)  h_prog[t] = t;
    __syncthreads();

    if (wv == 0) {
        u64t cA_lo = 0, cA_hi = 0, cB_lo = 0, cB_hi = 0;
        WSlot WA, WB, WC;
        fill_words(mask, lane, 0, WA);
        fill_words(mask, lane, 1, WB);
        fill_words(mask, lane, 2, WC);
        for (int T = 0; T < nc; T += 3) {
            res_step(mask, sdead, ck, &res_prog, h_prog, lane, T,
                     cA_lo, cA_hi, cB_lo, cB_hi, WA);
            if (T + 1 < nc)
                res_step(mask, sdead, ck, &res_prog, h_prog, lane, T + 1,
                         cA_lo, cA_hi, cB_lo, cB_hi, WB);
            if (T + 2 < nc)
                res_step(mask, sdead, ck, &res_prog, h_prog, lane, T + 2,
                         cA_lo, cA_hi, cB_lo, cB_hi, WC);
        }
    } else {
        int hh = wv - 1;
        for (int c = hh; c < nc; c += 7) {
            while (*(volatile int*)&res_prog <= c) __builtin_amdgcn_s_sleep(1);
            u64t kl = ((volatile u64t*)ck)[2 * c];
            u64t kh = ((volatile u64t*)ck)[2 * c + 1];
            if (kl | kh) {
                int base = c * 128;
                u64t ax = 0, ay = 0;
                while (kl | kh) {
                    ulonglong2 b[4];
                    #pragma unroll
                    for (int q = 0; q < 4; ++q) {
                        const ulonglong2* ptr;
                        if (kl) {
                            int b_ = __builtin_ctzll(kl); kl &= kl - 1;
                            ptr = (const ulonglong2*)(mask + (size_t)(base + b_) * 128) + lane;
                        } else if (kh) {
                            int b_ = __builtin_ctzll(kh); kh &= kh - 1;
                            ptr = (const ulonglong2*)(mask + (size_t)(base + 64 + b_) * 128) + lane;
                        } else {
                            ptr = (const ulonglong2*)zrow + lane;
                        }
                        b[q] = *ptr;
                    }
                    ax |= b[0].x | b[1].x | b[2].x | b[3].x;
                    ay |= b[0].y | b[1].y | b[2].y | b[3].y;
                }
                atomicOr(&sdead[2 * lane],     ax);
                atomicOr(&sdead[2 * lane + 1], ay);
            }
            __threadfence_block();
            if (lane == 0) ((volatile int*)h_prog)[hh] = c + 7;
        }
        if (lane == 0) ((volatile int*)h_prog)[hh] = 0x7FFFFFFF;
    }
    __syncthreads();
    if (t < 128) {
        u64t m = ck[t];
        while (m) {
            int b = __builtin_ctzll(m); m &= m - 1;
            int rr = t * 64 + b;
            out[rr * 5 + 0] = d_srt[rr * 5 + 0];
            out[rr * 5 + 1] = d_srt[rr * 5 + 1];
            out[rr * 5 + 2] = d_srt[rr * 5 + 2];
            out[rr * 5 + 3] = d_srt[rr * 5 + 3];
            out[rr * 5 + 4] = d_srt[rr * 5 + 4];
        }
    }
}

extern "C" void kernel_launch(void* const* d_in, const int* in_sizes, int n_in,
                              void* d_out, int out_size, void* d_ws, size_t ws_size,
                              hipStream_t stream) {
    const float* det     = (const float*)d_in[0];
    const float* offsets = (const float*)d_in[1];
    const float* scales  = (const float*)d_in[2];
    const float* bounds  = (const float*)d_in[3];
    float* out = (float*)d_out;
    char* ws = (char*)d_ws;
    float4*   boxes = (float4*)(ws + WS_BOX);
    float*    d_srt = (float*)(ws + WS_D);
    unsigned* bar   = (unsigned*)(ws + WS_BAR);
    u64t*     zrow  = (u64t*)(ws + WS_ZROW);
    u64t*     mask  = (u64t*)(ws + WS_MASK);

    hipMemsetAsync(bar, 0, 2 * sizeof(unsigned), stream);   // barrier state
    k_all<<<NBLK, 512, 0, stream>>>(det, offsets, scales, bounds,
                                    boxes, d_srt, zrow, mask, bar, out);
}

// Round 15
// 148.240 us; speedup vs baseline: 1.3460x; 1.3460x over previous
//
#include <hip/hip_runtime.h>
#include <cstdint>

// DetNet NMS, round 15. Revert r14 fusion (150us > sum of parts). Back to
// the r12/13 3-kernel structure; single change in k3:
//   THE BAND GOES TO LDS. r6-r13 evidence: resolver's serial chain is the
//   global sourcing of diag/carry words (~900 cyc), and the compiler sinks
//   every register-prefetch scheme to load-at-use (VGPR pinned at 40-52
//   regardless of launch_bounds — r13 null result). Fix: the resolver only
//   reads the diagonal band mask[row 64c+r][words c..c+2] — 96 KB for 64
//   chunks. Preload it into LDS with all 8 waves (parallel, off-chain),
//   then per-chunk staging is ds_read at-use (~120 cyc worst case, 7.5x
//   less than global). Helpers (r12 protocol, deadlock-free) still apply
//   full kept rows global->sdead off the chain. Chunks >= 64 fall back to
//   global staging (V>4096 only; V~4000 here).
// k2/k_mask identical to r12 (verified). absmax 0.0 rounds 1-4, 6-9, 11-14.

#define M_TOT 8192
#define NMS_T 0.3f
#define PCMAX 64            // preloaded 64-wide chunks: 64*64*3*8 = 96 KB

// ws layout (bytes)
#define WS_BOX   65536      // float4[8192]
#define WS_D     196608     // float[40960]
#define WS_VCNT  360448     // u32
#define WS_ZROW  393216     // u64[128] dummy zero row (zeroed by k2)
#define WS_MASK  524288     // u64[8192*128] = 8 MB

typedef unsigned long long u64t;

__device__ __forceinline__ uint32_t desc_key(float sv) {
    uint32_t u = __float_as_uint(sv);
    uint32_t m = (u & 0x80000000u) ? ~u : (u | 0x80000000u);
    return ~m;
}
__device__ __forceinline__ u64t rdl64(u64t v, int sl) {
    unsigned lo = (unsigned)__builtin_amdgcn_readlane((int)(unsigned)v, sl);
    unsigned hi = (unsigned)__builtin_amdgcn_readlane((int)(unsigned)(v >> 32), sl);
    return ((u64t)hi << 32) | lo;
}
__device__ __forceinline__ u64t rdfl64(u64t v) {
    unsigned lo = (unsigned)__builtin_amdgcn_readfirstlane((int)(unsigned)v);
    unsigned hi = (unsigned)__builtin_amdgcn_readfirstlane((int)(unsigned)(v >> 32));
    return ((u64t)hi << 32) | lo;
}

__device__ __forceinline__ void scatter_one(
    int i, int rank, u64t key,
    const float* __restrict__ det, const float* __restrict__ offsets,
    const float* __restrict__ scales,
    float4* __restrict__ boxes_srt, float* __restrict__ d_srt)
{
    uint32_t dkey = (uint32_t)(key >> 16);
    if (dkey >= 0x7FFFFFFFu) return;     // score <= 0: row stays zero
    int g = i >> 10;
    float d0 = __fadd_rn(offsets[g*5+0], __fmul_rn(det[i*5+0], scales[g*5+0]));
    float d1 = __fadd_rn(offsets[g*5+1], __fmul_rn(det[i*5+1], scales[g*5+1]));
    float d2 = __fadd_rn(offsets[g*5+2], __fmul_rn(det[i*5+2], scales[g*5+2]));
    float d3 = __fadd_rn(offsets[g*5+3], __fmul_rn(det[i*5+3], scales[g*5+3]));
    float d4 = __fadd_rn(offsets[g*5+4], __fmul_rn(det[i*5+4], scales[g*5+4]));
    d_srt[rank*5+0] = d0; d_srt[rank*5+1] = d1; d_srt[rank*5+2] = d2;
    d_srt[rank*5+3] = d3; d_srt[rank*5+4] = d4;
    float hw = __fmul_rn(d3, 0.5f), hh = __fmul_rn(d4, 0.5f);
    boxes_srt[rank] = make_float4(__fsub_rn(d1, hw), __fsub_rn(d2, hh),
                                  __fadd_rn(d1, hw), __fadd_rn(d2, hh));
}

__global__ __launch_bounds__(256) void k2_rank(
    const float* __restrict__ det, const float* __restrict__ offsets,
    const float* __restrict__ scales, const float* __restrict__ bounds,
    float4* __restrict__ boxes_srt, float* __restrict__ d_srt,
    unsigned int* __restrict__ vcnt, u64t* __restrict__ zrow,
    float* __restrict__ out)
{
    __shared__ u64t skey[M_TOT];
    __shared__ float soff[40], sscl[40], sbnd[32];
    __shared__ int sTop;
    int t = threadIdx.x;
    int lane = t & 63;
    if (t == 0) sTop = 0;
    if (t < 40) { soff[t] = offsets[t]; sscl[t] = scales[t]; }
    if (t < 32) { sbnd[t] = bounds[t]; }
    if (blockIdx.x == 0 && t < 128) zrow[t] = 0ull;
    __syncthreads();

    #pragma unroll 4
    for (int s = 0; s < 32; ++s) {
        int u = s * 256 + t;
        int g = u >> 10;
        float raw_s = det[u * 5 + 0];
        float cx    = det[u * 5 + 1];
        float cy    = det[u * 5 + 2];
        float score = __fadd_rn(soff[g * 5 + 0], __fmul_rn(raw_s, sscl[g * 5 + 0]));
        bool valid = (cx < sbnd[g*4+1]) && (cx > sbnd[g*4+0]) &&
                     (cy < sbnd[g*4+3]) && (cy > sbnd[g*4+2]);
        float sv = valid ? score : -1.0f;
        uint32_t dk = desc_key(sv);
        bool push = dk < 0x7FFFFFFFu;
        u64t key = ((u64t)dk << 16) | (unsigned)u;
        u64t bal = __ballot(push);
        if (bal) {
            int lw = 0;
            if (lane == 0) lw = atomicAdd(&sTop, __popcll(bal));
            int wbase = __builtin_amdgcn_readfirstlane(lw);
            if (push) {
                int off = __popcll(bal & ((1ull << lane) - 1ull));
                skey[wbase + off] = key;
            }
        }
    }
    __syncthreads();
    int V = sTop;
    int Vpad = (V + 15) & ~15;
    if (t < Vpad - V) skey[V + t] = ~0ull;
    {
        int zb = blockIdx.x * 160;
        for (int z = zb + t; z < zb + 160; z += 256) out[z] = 0.0f;
    }
    __syncthreads();
    if (t == 0) *vcnt = (unsigned)V;

    int grp = t >> 3;
    int jq  = t & 7;
    int i = blockIdx.x * 32 + grp;
    int g = i >> 10;
    float raw_s = det[i * 5 + 0];
    float cx    = det[i * 5 + 1];
    float cy    = det[i * 5 + 2];
    float score = __fadd_rn(soff[g * 5 + 0], __fmul_rn(raw_s, sscl[g * 5 + 0]));
    bool valid = (cx < sbnd[g*4+1]) && (cx > sbnd[g*4+0]) &&
                 (cy < sbnd[g*4+3]) && (cy > sbnd[g*4+2]);
    float sv = valid ? score : -1.0f;
    uint32_t dk = desc_key(sv);
    u64t ki = ((u64t)dk << 16) | (unsigned)i;
    const ulonglong2* skey2 = (const ulonglong2*)skey;
    int c = 0;
    int nit = Vpad >> 4;
    #pragma unroll 4
    for (int it = 0; it < nit; ++it) {
        ulonglong2 kj = skey2[it * 8 + jq];
        c += (kj.x < ki) + (kj.y < ki);
    }
    c += __shfl_xor(c, 1);
    c += __shfl_xor(c, 2);
    c += __shfl_xor(c, 4);
    if (jq == 0)
        scatter_one(i, c, ki, det, offsets, scales, boxes_srt, d_srt);
}

// mask build: block (bx,by): rows [bx*32,+32), words [by*16,+16)
__global__ __launch_bounds__(256) void k_mask(
    const float4* __restrict__ boxes_srt,
    const unsigned int* __restrict__ vcnt,
    u64t* __restrict__ mask)
{
    __shared__ float4 sb[16 * 65];
    __shared__ float  sa[16 * 65];
    int V = (int)*vcnt;
    int bx = blockIdx.x, by = blockIdx.y;
    if (bx * 32 >= V) return;
    if (by * 1024 >= V) return;
    if (by * 16 + 15 < (bx * 32) >> 6) return;
    int nc = (V + 63) >> 6;
    int tid = threadIdx.x;
    int cbase = by * 1024;
    for (int u = tid; u < 1024; u += 256) {
        float4 b = boxes_srt[cbase + u];
        int c = u >> 6, jj = u & 63;
        sb[c * 65 + jj] = b;
        sa[c * 65 + jj] = __fmul_rn(fmaxf(__fsub_rn(b.z, b.x), 0.0f),
                                    fmaxf(__fsub_rn(b.w, b.y), 0.0f));
    }
    __syncthreads();
    int r = bx * 32 + (tid >> 3);
    if (r >= V) return;
    float4 bi = boxes_srt[r];
    float ai = __fmul_rn(fmaxf(__fsub_rn(bi.z, bi.x), 0.0f),
                         fmaxf(__fsub_rn(bi.w, bi.y), 0.0f));
    int rw = r >> 6;
    #pragma unroll
    for (int k = 0; k < 2; ++k) {
        int wl = (tid & 7) + k * 8;
        int w = by * 16 + wl;
        if (w < rw || w >= nc) continue;
        u64t bits = 0;
        #pragma unroll 4
        for (int jj = 0; jj < 64; ++jj) {
            float4 bj = sb[wl * 65 + jj];
            float aj = sa[wl * 65 + jj];
            float iw = fmaxf(__fsub_rn(fminf(bi.z, bj.z), fmaxf(bi.x, bj.x)), 0.0f);
            float ih = fmaxf(__fsub_rn(fminf(bi.w, bj.w), fmaxf(bi.y, bj.y)), 0.0f);
            float inter = __fmul_rn(iw, ih);
            float uni   = __fsub_rn(__fadd_rn(ai, aj), inter);
            float iou   = __fdiv_rn(inter, fmaxf(uni, 1e-9f));
            int j = w * 64 + jj;
            if (j > r && iou > NMS_T) bits |= 1ull << jj;
        }
        mask[(size_t)r * 128 + w] = bits;
    }
}

// ---- k3: serial greedy resolve, band-in-LDS -----------------------------
// sband[(c*64+r)*3 + w] = mask word (c+w) of rank 64c+r, for c < PC.
// All words the resolver ever needs; valid (k_mask writes w >= rank>>6 = c).

__global__ __launch_bounds__(512) void k3_serial(
    const u64t* __restrict__ mask, const u64t* __restrict__ zrow,
    const float* __restrict__ d_srt, const unsigned int* __restrict__ vcnt,
    float* __restrict__ out)
{
    __shared__ u64t sband[PCMAX * 64 * 3];   // 96 KB
    __shared__ u64t sdead[128];              // dead bits, word w = ranks 64w..
    __shared__ u64t ck[128];                 // keptmask per 64-chunk
    __shared__ int  res_prog;
    __shared__ int  h_prog[7];
    int tid = threadIdx.x, wv = tid >> 6, lane = tid & 63;
    int V = (int)*vcnt;
    int nc = (V + 63) >> 6;                  // 64-wide chunks, <= 128
    int PC = min(nc, PCMAX);

    if (tid < 128) {
        int bw = tid * 64;
        u64t w0 = 0;
        if (bw >= V)           w0 = ~0ull;
        else if (bw + 64 > V)  w0 = (~0ull) << (V - bw);
        sdead[tid] = w0;
        ck[tid] = 0ull;
    }
    if (tid == 0) res_prog = 0;
    if (tid < 7)  h_prog[tid] = tid;
    // ---- preload the diagonal band (all 8 waves, parallel) ----
    for (int e = tid; e < PC * 64; e += 512) {
        int c = e >> 6;                      // chunk
        const u64t* rp = mask + (size_t)e * 128;   // rank = 64c+r = e
        sband[e * 3 + 0] = rp[c];            // c <= 63 -> c+2 <= 65 < 128
        sband[e * 3 + 1] = rp[c + 1];
        sband[e * 3 + 2] = rp[c + 2];
    }
    __syncthreads();

    if (wv == 0) {
        // ---- resolver: per-chunk words from LDS (<=120 cyc at-use) ----
        u64t cA = 0, cB = 0;                 // carries into T, T+1
        for (int T = 0; T < nc; ++T) {
            // stage this chunk's 3 words (LDS fast path; global fallback)
            u64t d, n1, n2;
            if (T < PC) {
                const u64t* p = sband + (size_t)(T * 64 + lane) * 3;
                d = p[0]; n1 = p[1]; n2 = p[2];
            } else {
                int r = min(T * 64 + lane, M_TOT - 1);
                const u64t* rp = mask + (size_t)r * 128;
                int w = min(T, 125);
                d = rp[w]; n1 = rp[w + 1]; n2 = rp[w + 2];
            }
            // spin until all chunks <= T-3 applied by helpers
            if (T >= 3) {
                int need = T - 2;
                while (true) {
                    int hp = (lane < 7) ? h_prog[lane] : 0x7FFFFFFF;
                    if (__ballot(hp < need) == 0ull) break;
                }
            }
            u64t dead = rdfl64(((volatile u64t*)sdead)[T]) | cA;
            u64t live = ~dead;
            int rem = V - T * 64;
            if (rem < 64) live &= (1ull << rem) - 1ull;
            u64t km = 0;
            while (live) {                   // SALU + readlane per keep
                int bs = (int)__builtin_ctzll(live);
                km |= 1ull << bs;
                u64t rm = rdl64(d, bs);
                live &= ~rm & ~(1ull << bs);
            }
            if (lane == 0) ck[T] = km;
            __threadfence_block();
            if (lane == 0) *(volatile int*)&res_prog = T + 1;
            // carries to T+1 / T+2 (off the per-keep chain)
            u64t c1 = 0, c2 = 0, k2m = km;
            while (k2m) {
                int b = (int)__builtin_ctzll(k2m); k2m &= k2m - 1;
                c1 |= rdl64(n1, b);
                c2 |= rdl64(n2, b);
            }
            cA = cB | c1;
            cB = c2;
        }
    } else {
        // ---- helper (wv-1): chunks c == wv-1 (mod 7); full-row ORs ----
        int hh = wv - 1;
        for (int c = hh; c < nc; c += 7) {
            while (*(volatile int*)&res_prog <= c) __builtin_amdgcn_s_sleep(1);
            u64t kl = ((volatile u64t*)ck)[c];
            if (kl) {
                int base = c * 64;
                u64t ax = 0, ay = 0;
                while (kl) {
                    ulonglong2 b[4];
                    #pragma unroll
                    for (int q = 0; q < 4; ++q) {   // 4-slot dummy-padded batch
                        const ulonglong2* ptr;
                        if (kl) {
                            int b_ = __builtin_ctzll(kl); kl &= kl - 1;
                            ptr = (const ulonglong2*)(mask + (size_t)(base + b_) * 128) + lane;
                        } else {
                            ptr = (const ulonglong2*)zrow + lane;
                        }
                        b[q] = *ptr;
                    }
                    ax |= b[0].x | b[1].x | b[2].x | b[3].x;
                    ay |= b[0].y | b[1].y | b[2].y | b[3].y;
                }
                atomicOr(&sdead[2 * lane],     ax);
                atomicOr(&sdead[2 * lane + 1], ay);
            }
            __threadfence_block();
            if (lane == 0) ((volatile int*)h_prog)[hh] = c + 7;
        }
        if (lane == 0) ((volatile int*)h_prog)[hh] = 0x7FFFFFFF;
    }
    __syncthreads();
    // output: expand keptmasks (order irrelevant for stores)
    if (tid < 128) {
        u64t m = ck[tid];
        while (m) {
            int b = __builtin_ctzll(m); m &= m - 1;
            int rr = tid * 64 + b;
            out[rr * 5 + 0] = d_srt[rr * 5 + 0];
            out[rr * 5 + 1] = d_srt[rr * 5 + 1];
            out[rr * 5 + 2] = d_srt[rr * 5 + 2];
            out[rr * 5 + 3] = d_srt[rr * 5 + 3];
            out[rr * 5 + 4] = d_srt[rr * 5 + 4];
        }
    }
}

extern "C" void kernel_launch(void* const* d_in, const int* in_sizes, int n_in,
                              void* d_out, int out_size, void* d_ws, size_t ws_size,
                              hipStream_t stream) {
    const float* det     = (const float*)d_in[0];
    const float* offsets = (const float*)d_in[1];
    const float* scales  = (const float*)d_in[2];
    const float* bounds  = (const float*)d_in[3];
    float* out = (float*)d_out;
    char* ws = (char*)d_ws;
    float4*       boxes = (float4*)(ws + WS_BOX);
    float*        d_srt = (float*)(ws + WS_D);
    unsigned int* vcnt  = (unsigned int*)(ws + WS_VCNT);
    u64t*         zrow  = (u64t*)(ws + WS_ZROW);
    u64t*         mask  = (u64t*)(ws + WS_MASK);

    k2_rank<<<256, 256, 0, stream>>>(det, offsets, scales, bounds, boxes, d_srt, vcnt, zrow, out);
    k_mask<<<dim3(256, 8), 256, 0, stream>>>(boxes, vcnt, mask);
    k3_serial<<<1, 512, 0, stream>>>(mask, zrow, d_srt, vcnt, out);
}